// Round 13
// baseline (193.870 us; speedup 1.0000x reference)
//
#include <hip/hip_runtime.h>
#include <hip/hip_bf16.h>
#include <cstdint>

// Causal self-attention: x[4,2048,1024] @ Wqkv[1024,3072] -> QKV -> 16-head
// causal attention (HD=64) -> @ Wout[1024,1024] -> out fp32.
// R13: QKV GEMM ported to the 256x256 8-wave phase-split template: BK=64,
// 2-buffer 128KB LDS (1 block/CU), 4 phases per K-tile each {ds_read quadrant
// -> s_barrier -> setprio+16 MFMA -> s_barrier} (64 MFMA/wave/K-tile vs 16),
// all 8 next-tile global_load_lds issued at phase 0, single vmcnt(0) at end
// of phase 3 (~800cyc cover; raw barriers never drain vmcnt mid-tile).
// Swizzle: verified 128B-row involution granule^(row&7), pre-swizzled source.
// Out-proj stays on the R12 128^2 kernel; attention unchanged from R8.

typedef __attribute__((ext_vector_type(8))) short bf16x8;
typedef __attribute__((ext_vector_type(4))) float f32x4;
typedef __attribute__((ext_vector_type(4))) uint32_t u32x4;

#define MFMA_BF16(a, b, c) __builtin_amdgcn_mfma_f32_16x16x32_bf16((a), (b), (c), 0, 0, 0)

__device__ __forceinline__ ushort f2bf(float f) {
  union { float f; uint32_t u; } x;
  x.f = f;
  uint32_t u = x.u;
  return (ushort)((u + 0x7FFFu + ((u >> 16) & 1u)) >> 16);
}

__device__ __forceinline__ uint32_t cvt_pk_bf16(float lo, float hi) {
  uint32_t r;
  asm("v_cvt_pk_bf16_f32 %0, %1, %2" : "=v"(r) : "v"(lo), "v"(hi));
  return r;
}

__device__ __forceinline__ void gload16(const ushort* g, ushort* l) {
  __builtin_amdgcn_global_load_lds(
      (const __attribute__((address_space(1))) void*)g,
      (__attribute__((address_space(3))) void*)l, 16, 0, 0);
}

// ---------------------------------------------------------------- convert x
__global__ __launch_bounds__(256) void convert_f32_bf16(
    const float* __restrict__ in, ushort* __restrict__ out, int n4) {
  int i = blockIdx.x * 256 + threadIdx.x;
  if (i < n4) {
    float4 v = ((const float4*)in)[i];
    ushort4 o;
    o.x = f2bf(v.x); o.y = f2bf(v.y); o.z = f2bf(v.z); o.w = f2bf(v.w);
    ((ushort4*)out)[i] = o;
  }
}

// ------------------------------------------------- W [K][N] f32 -> Wt [N][K] bf16
__global__ __launch_bounds__(256) void transpose_w(
    const float* __restrict__ W, ushort* __restrict__ Wt, int K, int N) {
  __shared__ float tile[32][33];
  const int n0 = blockIdx.x * 32, k0 = blockIdx.y * 32;
  const int tx = threadIdx.x & 31, ty = threadIdx.x >> 5;  // ty 0..7
#pragma unroll
  for (int i = 0; i < 4; ++i)
    tile[ty + i * 8][tx] = W[(size_t)(k0 + ty + i * 8) * N + n0 + tx];
  __syncthreads();
#pragma unroll
  for (int i = 0; i < 4; ++i)
    Wt[(size_t)(n0 + ty + i * 8) * K + k0 + tx] = f2bf(tile[tx][ty + i * 8]);
}

// ---------------------------------------------------- 256x256 8-phase GEMM (QKV)
// A [M][K] bf16, Bt [N][K] bf16. 512 threads = 8 waves (2M x 4N); per-wave
// C = 128x64 (acc[8][4]). LDS [2][256][64] per operand = 128KB total.
// Per K-tile (BK=64): 4 phases, quadrant order (0,0),(0,1),(1,1),(1,0);
// each phase: ds_read frags -> s_barrier -> setprio(1)+16 MFMA+setprio(0)
// -> s_barrier. All 8 next-tile gload_lds issued at phase 0; one vmcnt(0)
// at end of phase 3 (just before the tile-boundary barrier).
// Epilogue: QKV split (q pre-scaled by 0.125*log2e; V^T key-permuted).

#define LD_AF(MH)                                                            \
  {                                                                          \
    _Pragma("unroll")                                                        \
    for (int m = 0; m < 4; ++m) {                                            \
      const int row = wr * 128 + (MH) * 64 + m * 16 + l15;                   \
      _Pragma("unroll")                                                      \
      for (int kk = 0; kk < 2; ++kk)                                         \
        af[m][kk] = *(const bf16x8*)&as[row * 64 +                           \
                     (((kk * 4 + lhi) ^ (row & 7)) << 3)];                   \
    }                                                                        \
  }

#define LD_BF(DST, NH)                                                       \
  {                                                                          \
    _Pragma("unroll")                                                        \
    for (int n = 0; n < 2; ++n) {                                            \
      const int row = wc * 64 + (NH) * 32 + n * 16 + l15;                    \
      _Pragma("unroll")                                                      \
      for (int kk = 0; kk < 2; ++kk)                                         \
        DST[n][kk] = *(const bf16x8*)&bs[row * 64 +                          \
                     (((kk * 4 + lhi) ^ (row & 7)) << 3)];                   \
    }                                                                        \
  }

#define MFMA16(MH, NH, BF)                                                   \
  {                                                                          \
    __builtin_amdgcn_s_setprio(1);                                           \
    _Pragma("unroll")                                                        \
    for (int m = 0; m < 4; ++m)                                              \
      _Pragma("unroll")                                                      \
      for (int n = 0; n < 2; ++n)                                            \
        _Pragma("unroll")                                                    \
        for (int kk = 0; kk < 2; ++kk)                                       \
          acc[(MH) * 4 + m][(NH) * 2 + n] = MFMA_BF16(                       \
              af[m][kk], BF[n][kk], acc[(MH) * 4 + m][(NH) * 2 + n]);        \
    __builtin_amdgcn_s_setprio(0);                                           \
  }

__global__ __launch_bounds__(512)
__attribute__((amdgpu_waves_per_eu(2, 2)))
void gemm256_qkv(
    const ushort* __restrict__ A, const ushort* __restrict__ Bt,
    ushort* __restrict__ qb, ushort* __restrict__ kb, ushort* __restrict__ vb,
    int M, int N, int K) {
  __shared__ ushort As[2][256 * 64];  // 64 KB
  __shared__ ushort Bs[2][256 * 64];  // 64 KB
  const int tid = threadIdx.x;
  const int lane = tid & 63;
  const int w = tid >> 6;              // 0..7
  const int wr = w >> 2, wc = w & 3;   // 2M x 4N
  const int l15 = lane & 15, lhi = lane >> 4;

  // XCD row-slab decode (grid 384 = 8 XCD * 48; M/256=32 -> 4 row-tiles/XCD)
  const int ncolt = N >> 8;            // 12
  const int rpx = (M >> 8) >> 3;       // 4
  const int b = blockIdx.x;
  const int xcd = b & 7;
  const int loc = b >> 3;
  const int rowg = loc / ncolt;
  const int colt = loc - rowg * ncolt;
  const int row0 = (xcd * rpx + rowg) * 256;
  const int col0 = colt * 256;

  // staging: wave w stages A rows [32w,32w+32) + B rows [32w,32w+32) as
  // 4 chunks each (8 rows x 64 cols = 1KB). lane: cr=row-in-chunk, sl=granule.
  const int cr = lane >> 3;
  const int sl = lane & 7;
  const int gofs = (sl ^ cr) << 3;     // pre-swizzled granule (row&7 == cr)
  const ushort* gA = A  + (size_t)(row0 + w * 32 + cr) * K + gofs;
  const ushort* gB = Bt + (size_t)(col0 + w * 32 + cr) * K + gofs;
  const int lb = (w * 32) * 64;        // ushort base of wave's chunk 0

#define G_STAGE8(BUF, T)                                                     \
  {                                                                          \
    _Pragma("unroll")                                                        \
    for (int c = 0; c < 4; ++c) {                                            \
      gload16(gA + (size_t)(c * 8) * K + (size_t)(T) * 64,                   \
              &As[BUF][lb + c * 512]);                                       \
      gload16(gB + (size_t)(c * 8) * K + (size_t)(T) * 64,                   \
              &Bs[BUF][lb + c * 512]);                                       \
    }                                                                        \
  }

  f32x4 acc[8][4] = {};

  const int nk = K >> 6;               // 16
  G_STAGE8(0, 0)
  asm volatile("s_waitcnt vmcnt(0)" ::: "memory");
  __builtin_amdgcn_s_barrier();

  for (int t = 0; t < nk; ++t) {
    const int cur = t & 1;
    const ushort* as = &As[cur][0];
    const ushort* bs = &Bs[cur][0];
    const bool pre = (t + 1 < nk);     // block-uniform

    bf16x8 af[4][2], bf0[2][2], bf1[2][2];

    // ---- phase 0: quadrant (0,0); issue all 8 next-tile loads
    if (pre) G_STAGE8(cur ^ 1, t + 1)
    LD_AF(0)
    LD_BF(bf0, 0)
    __builtin_amdgcn_s_barrier();
    MFMA16(0, 0, bf0)
    __builtin_amdgcn_s_barrier();

    // ---- phase 1: quadrant (0,1)
    LD_BF(bf1, 1)
    __builtin_amdgcn_s_barrier();
    MFMA16(0, 1, bf1)
    __builtin_amdgcn_s_barrier();

    // ---- phase 2: quadrant (1,1)
    LD_AF(1)
    __builtin_amdgcn_s_barrier();
    MFMA16(1, 1, bf1)
    __builtin_amdgcn_s_barrier();

    // ---- phase 3: quadrant (1,0); boundary vmcnt as late as possible
    __builtin_amdgcn_s_barrier();
    MFMA16(1, 0, bf0)
    if (pre) asm volatile("s_waitcnt vmcnt(0)" ::: "memory");
    __builtin_amdgcn_s_barrier();
  }
#undef G_STAGE8

  // ---- QKV split epilogue (c: seg=c/1024, h=(c%1024)/64, d=c%64)
  const float QSCALE = 0.18033688011112042f;  // (1/sqrt(64)) * log2(e)
#pragma unroll
  for (int m = 0; m < 8; ++m) {
    const int r0 = row0 + wr * 128 + m * 16 + lhi * 4;
    const int b_ = r0 >> 11;
    const int t0 = r0 & 2047;
#pragma unroll
    for (int n = 0; n < 4; ++n) {
      const int c = col0 + wc * 64 + n * 16 + l15;
      const int seg = c >> 10;
      const int cc = c & 1023;
      const int h = cc >> 6, d = cc & 63;
      const size_t bhi = (size_t)(b_ * 16 + h);
      if (seg == 0) {
#pragma unroll
        for (int j = 0; j < 4; ++j)
          qb[(bhi * 2048 + t0 + j) * 64 + d] = f2bf(acc[m][n][j] * QSCALE);
      } else if (seg == 1) {
#pragma unroll
        for (int j = 0; j < 4; ++j)
          kb[(bhi * 2048 + t0 + j) * 64 + d] = f2bf(acc[m][n][j]);
      } else {
        // permuted key position within the 32-token chunk (t0 % 4 == 0)
        const int pos = (t0 & ~31) + ((t0 & 12) << 1) + ((t0 >> 4) & 1) * 4;
        ushort4 pk;
        pk.x = f2bf(acc[m][n][0]);
        pk.y = f2bf(acc[m][n][1]);
        pk.z = f2bf(acc[m][n][2]);
        pk.w = f2bf(acc[m][n][3]);
        *(ushort4*)(vb + (bhi * 64 + d) * 2048 + pos) = pk;  // V^T key-permuted
      }
    }
  }
}

// ---------------------------------------------------------------- GEMM bf16 (128^2)
// Used for the out-projection (N=1024: 512 blocks keep the chip full).
// R12 structure: BK=32, triple-buffered, counted vmcnt, swizzle (row>>1)&3.
template <int MODE>
__global__ __launch_bounds__(256)
__attribute__((amdgpu_waves_per_eu(3, 3)))
void gemm_bf16_kernel(
    const ushort* __restrict__ A, const ushort* __restrict__ Bt,
    float* __restrict__ C,
    ushort* __restrict__ qb, ushort* __restrict__ kb, ushort* __restrict__ vb,
    int M, int N, int K) {
  __shared__ ushort As[3][128 * 32];
  __shared__ ushort Bs[3][128 * 32];
  const int tid = threadIdx.x;
  const int lane = tid & 63;
  const int w = tid >> 6;
  const int wr = w >> 1, wc = w & 1;
  const int l15 = lane & 15, lhi = lane >> 4;

  const int ncolt = N >> 7;
  const int rpx = (M >> 7) >> 3;
  const int b = blockIdx.x;
  const int xcd = b & 7;
  const int loc = b >> 3;
  const int rowg = loc / ncolt;
  const int colt = loc - rowg * ncolt;
  const int row0 = (xcd * rpx + rowg) * 128;
  const int col0 = colt * 128;

  const int cr = lane >> 2;
  const int sl = lane & 3;
  const int gofs = (sl ^ ((cr >> 1) & 3)) << 3;
  const ushort* gA = A  + (size_t)(row0 + w * 32 + cr) * K + gofs;
  const ushort* gB = Bt + (size_t)(col0 + w * 32 + cr) * K + gofs;
  const int lbase = (w * 32) * 32;

  f32x4 acc[4][4] = {};

#define G_STAGE(BUF, T)                                                      \
  {                                                                          \
    gload16(gA + (size_t)(T) * 32, &As[BUF][lbase]);                         \
    gload16(gA + (size_t)16 * K + (size_t)(T) * 32, &As[BUF][lbase + 512]);  \
    gload16(gB + (size_t)(T) * 32, &Bs[BUF][lbase]);                         \
    gload16(gB + (size_t)16 * K + (size_t)(T) * 32, &Bs[BUF][lbase + 512]);  \
  }

  const int nk = K >> 5;
  G_STAGE(0, 0)
  G_STAGE(1, 1)

  for (int t = 0; t < nk; ++t) {
    const int cur = t % 3;
    if (t + 1 < nk) {
      asm volatile("s_waitcnt vmcnt(4)" ::: "memory");
    } else {
      asm volatile("s_waitcnt vmcnt(0)" ::: "memory");
    }
    __builtin_amdgcn_s_barrier();

    bf16x8 af[4], bfr[4];
#pragma unroll
    for (int m = 0; m < 4; ++m) {
      const int row = wr * 64 + m * 16 + l15;
      af[m] = *(const bf16x8*)&As[cur][row * 32 + ((lhi ^ ((row >> 1) & 3)) << 3)];
    }
#pragma unroll
    for (int n = 0; n < 4; ++n) {
      const int row = wc * 64 + n * 16 + l15;
      bfr[n] = *(const bf16x8*)&Bs[cur][row * 32 + ((lhi ^ ((row >> 1) & 3)) << 3)];
    }

    if (t + 2 < nk) {
      const int nb = (t + 2) % 3;
      G_STAGE(nb, t + 2)
    }

    __builtin_amdgcn_s_setprio(1);
#pragma unroll
    for (int m = 0; m < 4; ++m)
#pragma unroll
      for (int n = 0; n < 4; ++n)
        acc[m][n] = MFMA_BF16(af[m], bfr[n], acc[m][n]);
    __builtin_amdgcn_s_setprio(0);
  }
#undef G_STAGE

  if (MODE == 1) {
#pragma unroll
    for (int m = 0; m < 4; ++m) {
      const int r0 = row0 + wr * 64 + m * 16 + lhi * 4;
#pragma unroll
      for (int n = 0; n < 4; ++n) {
        const int c = col0 + wc * 64 + n * 16 + l15;
#pragma unroll
        for (int j = 0; j < 4; ++j)
          C[(size_t)(r0 + j) * N + c] = acc[m][n][j];
      }
    }
  } else {
    const float QSCALE = 0.18033688011112042f;
#pragma unroll
    for (int m = 0; m < 4; ++m) {
      const int r0 = row0 + wr * 64 + m * 16 + lhi * 4;
      const int b_ = r0 >> 11;
      const int t0 = r0 & 2047;
#pragma unroll
      for (int n = 0; n < 4; ++n) {
        const int c = col0 + wc * 64 + n * 16 + l15;
        const int seg = c >> 10;
        const int cc = c & 1023;
        const int h = cc >> 6, d = cc & 63;
        const size_t bhi = (size_t)(b_ * 16 + h);
        if (seg == 0) {
#pragma unroll
          for (int j = 0; j < 4; ++j)
            qb[(bhi * 2048 + t0 + j) * 64 + d] = f2bf(acc[m][n][j] * QSCALE);
        } else if (seg == 1) {
#pragma unroll
          for (int j = 0; j < 4; ++j)
            kb[(bhi * 2048 + t0 + j) * 64 + d] = f2bf(acc[m][n][j]);
        } else {
          const int pos = (t0 & ~31) + ((t0 & 12) << 1) + ((t0 >> 4) & 1) * 4;
          ushort4 pk;
          pk.x = f2bf(acc[m][n][0]);
          pk.y = f2bf(acc[m][n][1]);
          pk.z = f2bf(acc[m][n][2]);
          pk.w = f2bf(acc[m][n][3]);
          *(ushort4*)(vb + (bhi * 64 + d) * 2048 + pos) = pk;
        }
      }
    }
  }
}

// ------------------------------------------------------------- attention
// (unchanged from R8 — spill fixed via waves_per_eu(4,4) + de-arrayed state)
#define QK_TILE(SV, KT)                                                      \
  {                                                                          \
    const int krow = (KT) * 16 + l15;                                        \
    const int sw = krow & 7;                                                 \
    bf16x8 kf0 = *(const bf16x8*)&Ks[cur][krow * 64 + ((lhi ^ sw) * 8)];     \
    bf16x8 kf1 = *(const bf16x8*)&Ks[cur][krow * 64 + (((4 + lhi) ^ sw) * 8)];\
    f32x4 acc_ = {};                                                         \
    acc_ = MFMA_BF16(kf0, qf0, acc_);                                        \
    acc_ = MFMA_BF16(kf1, qf1, acc_);                                        \
    SV = acc_;                                                               \
  }

#define MASK_TILE(SV, KT)                                                    \
  {                                                                          \
    if (key0 + (KT) * 16 + lhi * 4 + 0 > qrow) SV[0] = -INFINITY;            \
    if (key0 + (KT) * 16 + lhi * 4 + 1 > qrow) SV[1] = -INFINITY;            \
    if (key0 + (KT) * 16 + lhi * 4 + 2 > qrow) SV[2] = -INFINITY;            \
    if (key0 + (KT) * 16 + lhi * 4 + 3 > qrow) SV[3] = -INFINITY;            \
  }

#define SM_TILE(SV, W0, W1)                                                  \
  {                                                                          \
    float p0 = exp2f(SV[0] - m_state);                                       \
    float p1 = exp2f(SV[1] - m_state);                                       \
    float p2 = exp2f(SV[2] - m_state);                                       \
    float p3 = exp2f(SV[3] - m_state);                                       \
    lloc += (p0 + p1) + (p2 + p3);                                           \
    W0 = cvt_pk_bf16(p0, p1);                                                \
    W1 = cvt_pk_bf16(p2, p3);                                                \
  }

#define PV_TILE(ON, N)                                                       \
  {                                                                          \
    const int vrow = (N) * 16 + l15;                                         \
    const int sw = vrow & 7;                                                 \
    bf16x8 vf0 = *(const bf16x8*)&Vs[cur][vrow * 64 + ((lhi ^ sw) * 8)];     \
    bf16x8 vf1 = *(const bf16x8*)&Vs[cur][vrow * 64 + (((4 + lhi) ^ sw) * 8)];\
    ON = MFMA_BF16(pf0, vf0, ON);                                            \
    ON = MFMA_BF16(pf1, vf1, ON);                                            \
  }

__global__ __launch_bounds__(256)
__attribute__((amdgpu_waves_per_eu(4, 4)))
void attn_kernel(
    const ushort* __restrict__ Qb, const ushort* __restrict__ Kb,
    const ushort* __restrict__ Vt, ushort* __restrict__ Ab) {
  const int bid = blockIdx.x;
  const int qt = 31 - (bid >> 6);
  const int bh = bid & 63;
  const int tid = threadIdx.x;
  const int lane = tid & 63;
  const int w = tid >> 6;
  const int l15 = lane & 15, lhi = lane >> 4;
  const int qloc = qt * 64 + w * 16;

  __shared__ ushort Ks[2][64 * 64];
  __shared__ ushort Vs[2][64 * 64];

  const size_t qkbase = (size_t)bh * (2048 * 64);
  const size_t vtb = (size_t)bh * (64 * 2048);

  const int srow = w * 16 + (lane >> 3);
  const int sd0 = lane & 7;
  const int slot = (sd0 ^ (srow & 7)) * 8;

  const ushort* kp0 = Kb + qkbase + (size_t)srow * 64 + sd0 * 8;
  const ushort* kp1 = kp0 + 8 * 64;
  const ushort* vp0 = Vt + vtb + (size_t)srow * 2048 + sd0 * 8;
  const ushort* vp1 = vp0 + 8 * 2048;

  bf16x8 qf0 = *(const bf16x8*)(Qb + qkbase + (size_t)(qloc + l15) * 64 + lhi * 8);
  bf16x8 qf1 = *(const bf16x8*)(Qb + qkbase + (size_t)(qloc + l15) * 64 + 32 + lhi * 8);

  uint4 kr0 = *(const uint4*)kp0;
  uint4 kr1 = *(const uint4*)kp1;
  uint4 vr0 = *(const uint4*)vp0;
  uint4 vr1 = *(const uint4*)vp1;
  *(uint4*)&Ks[0][srow * 64 + slot] = kr0;
  *(uint4*)&Ks[0][(srow + 8) * 64 + slot] = kr1;
  *(uint4*)&Vs[0][srow * 64 + slot] = vr0;
  *(uint4*)&Vs[0][(srow + 8) * 64 + slot] = vr1;
  __syncthreads();

  float m_state = -INFINITY, l_state = 0.f;
  f32x4 o0 = {}, o1 = {}, o2 = {}, o3 = {};
  const int qrow = qloc + l15;
  int cur = 0;

  for (int kbt = 0; kbt <= qt; ++kbt) {
    const int key0 = kbt * 64;
    const bool last = (kbt == qt);

    if (!last) {
      const size_t koff = (size_t)(kbt + 1) * 64 * 64;
      kr0 = *(const uint4*)(kp0 + koff);
      kr1 = *(const uint4*)(kp1 + koff);
      vr0 = *(const uint4*)(vp0 + (kbt + 1) * 64);
      vr1 = *(const uint4*)(vp1 + (kbt + 1) * 64);
    }

    f32x4 s0, s1, s2, s3;
    __builtin_amdgcn_s_setprio(1);
    QK_TILE(s0, 0)
    QK_TILE(s1, 1)
    QK_TILE(s2, 2)
    QK_TILE(s3, 3)
    __builtin_amdgcn_s_setprio(0);

    if (last) {
      MASK_TILE(s0, 0)
      MASK_TILE(s1, 1)
      MASK_TILE(s2, 2)
      MASK_TILE(s3, 3)
    }

    float t0 = fmaxf(fmaxf(s0[0], s0[1]), fmaxf(s0[2], s0[3]));
    float t1 = fmaxf(fmaxf(s1[0], s1[1]), fmaxf(s1[2], s1[3]));
    float t2 = fmaxf(fmaxf(s2[0], s2[1]), fmaxf(s2[2], s2[3]));
    float t3 = fmaxf(fmaxf(s3[0], s3[1]), fmaxf(s3[2], s3[3]));
    float tmax = fmaxf(fmaxf(t0, t1), fmaxf(t2, t3));
    tmax = fmaxf(tmax, __shfl_xor(tmax, 16));
    tmax = fmaxf(tmax, __shfl_xor(tmax, 32));

    if (!__all(tmax <= m_state + 8.0f)) {
      const float mnew = fmaxf(m_state, tmax);
      const float alpha = exp2f(m_state - mnew);
      const float a0 = __shfl(alpha, lhi * 4 + 0);
      const float a1 = __shfl(alpha, lhi * 4 + 1);
      const float a2 = __shfl(alpha, lhi * 4 + 2);
      const float a3 = __shfl(alpha, lhi * 4 + 3);
      o0[0] *= a0; o0[1] *= a1; o0[2] *= a2; o0[3] *= a3;
      o1[0] *= a0; o1[1] *= a1; o1[2] *= a2; o1[3] *= a3;
      o2[0] *= a0; o2[1] *= a1; o2[2] *= a2; o2[3] *= a3;
      o3[0] *= a0; o3[1] *= a1; o3[2] *= a2; o3[3] *= a3;
      l_state *= alpha;
      m_state = mnew;
    }

    float lloc = 0.f;
    uint32_t w0, w1, w2, w3, w4, w5, w6, w7;
    SM_TILE(s0, w0, w1)
    SM_TILE(s1, w2, w3)
    SM_TILE(s2, w4, w5)
    SM_TILE(s3, w6, w7)
    lloc += __shfl_xor(lloc, 16);
    lloc += __shfl_xor(lloc, 32);
    l_state += lloc;

    u32x4 pw0 = {w0, w1, w2, w3};
    u32x4 pw1 = {w4, w5, w6, w7};
    bf16x8 pf0 = __builtin_bit_cast(bf16x8, pw0);
    bf16x8 pf1 = __builtin_bit_cast(bf16x8, pw1);

    __builtin_amdgcn_s_setprio(1);
    PV_TILE(o0, 0)
    PV_TILE(o1, 1)
    PV_TILE(o2, 2)
    PV_TILE(o3, 3)
    __builtin_amdgcn_s_setprio(0);

    if (!last) {
      const int nxt = cur ^ 1;
      *(uint4*)&Ks[nxt][srow * 64 + slot] = kr0;
      *(uint4*)&Ks[nxt][(srow + 8) * 64 + slot] = kr1;
      *(uint4*)&Vs[nxt][srow * 64 + slot] = vr0;
      *(uint4*)&Vs[nxt][(srow + 8) * 64 + slot] = vr1;
      cur = nxt;
      __syncthreads();
    }
  }

  const int b_ = bh >> 4, h_ = bh & 15;
#pragma unroll
  for (int j = 0; j < 4; ++j) {
    const float linv = 1.0f / __shfl(l_state, lhi * 4 + j);
    const int t = qloc + lhi * 4 + j;
    const size_t ro = ((size_t)b_ * 2048 + t) * 1024 + h_ * 64;
    Ab[ro + 0 * 16 + l15] = f2bf(o0[j] * linv);
    Ab[ro + 1 * 16 + l15] = f2bf(o1[j] * linv);
    Ab[ro + 2 * 16 + l15] = f2bf(o2[j] * linv);
    Ab[ro + 3 * 16 + l15] = f2bf(o3[j] * linv);
  }
}

// ---------------------------------------------------------------- launch
extern "C" void kernel_launch(void* const* d_in, const int* in_sizes, int n_in,
                              void* d_out, int out_size, void* d_ws, size_t ws_size,
                              hipStream_t stream) {
  const float* x = (const float*)d_in[0];
  const float* Wqkv = (const float*)d_in[1];
  const float* Wout = (const float*)d_in[2];
  float* out = (float*)d_out;

  // workspace layout (bf16 elements), total ~88 MB
  ushort* xb    = (ushort*)d_ws;                     // [8192][1024]
  ushort* wqkvT = xb + (size_t)8192 * 1024;          // [3072][1024]
  ushort* woutT = wqkvT + (size_t)3072 * 1024;       // [1024][1024]
  ushort* qb    = woutT + (size_t)1024 * 1024;       // [64][2048][64]
  ushort* kbuf  = qb + (size_t)64 * 2048 * 64;       // [64][2048][64]
  ushort* vbuf  = kbuf + (size_t)64 * 2048 * 64;     // [64][64][2048] (V^T, key-permuted)
  ushort* ab    = vbuf + (size_t)64 * 2048 * 64;     // [8192][1024]

  convert_f32_bf16<<<8192, 256, 0, stream>>>(x, xb, 8192 * 1024 / 4);
  transpose_w<<<dim3(96, 32), 256, 0, stream>>>(Wqkv, wqkvT, 1024, 3072);
  transpose_w<<<dim3(32, 32), 256, 0, stream>>>(Wout, woutT, 1024, 1024);
  gemm256_qkv<<<384, 512, 0, stream>>>(
      xb, wqkvT, qb, kbuf, vbuf, 8192, 3072, 1024);
  attn_kernel<<<2048, 256, 0, stream>>>(qb, kbuf, vbuf, ab);
  gemm_bf16_kernel<1><<<512, 256, 0, stream>>>(
      ab, woutT, out, nullptr, nullptr, nullptr, 8192, 1024, 1024);
}

// Round 14
// 178.102 us; speedup vs baseline: 1.0885x; 1.0885x over previous
//
#include <hip/hip_runtime.h>
#include <hip/hip_bf16.h>
#include <cstdint>

// Causal self-attention: x[4,2048,1024] @ Wqkv[1024,3072] -> QKV -> 16-head
// causal attention (HD=64) -> @ Wout[1024,1024] -> out fp32.
// R14: composition of best measured components after the R13 8-phase port
// regressed (116us, MfmaUtil 17% -- vmcnt(0) drain at 1 block/CU lockstep).
// G0 (QKV): R12's 128^2 BK=32 triple-buffer counted-vmcnt kernel (80us).
// G1 (out-proj): R9's BK=64 double-buffer kernel (fewer barrier pairs; the
// R9-vs-R11/12 ledger shows ~15us non-G0 advantage attributable to it).
// attn: R8's (spill-free, register P-frags, ~50us). Pre-kernels unchanged.

typedef __attribute__((ext_vector_type(8))) short bf16x8;
typedef __attribute__((ext_vector_type(4))) float f32x4;
typedef __attribute__((ext_vector_type(4))) uint32_t u32x4;

#define MFMA_BF16(a, b, c) __builtin_amdgcn_mfma_f32_16x16x32_bf16((a), (b), (c), 0, 0, 0)

__device__ __forceinline__ ushort f2bf(float f) {
  union { float f; uint32_t u; } x;
  x.f = f;
  uint32_t u = x.u;
  return (ushort)((u + 0x7FFFu + ((u >> 16) & 1u)) >> 16);
}

__device__ __forceinline__ uint32_t cvt_pk_bf16(float lo, float hi) {
  uint32_t r;
  asm("v_cvt_pk_bf16_f32 %0, %1, %2" : "=v"(r) : "v"(lo), "v"(hi));
  return r;
}

__device__ __forceinline__ void gload16(const ushort* g, ushort* l) {
  __builtin_amdgcn_global_load_lds(
      (const __attribute__((address_space(1))) void*)g,
      (__attribute__((address_space(3))) void*)l, 16, 0, 0);
}

// ---------------------------------------------------------------- convert x
__global__ __launch_bounds__(256) void convert_f32_bf16(
    const float* __restrict__ in, ushort* __restrict__ out, int n4) {
  int i = blockIdx.x * 256 + threadIdx.x;
  if (i < n4) {
    float4 v = ((const float4*)in)[i];
    ushort4 o;
    o.x = f2bf(v.x); o.y = f2bf(v.y); o.z = f2bf(v.z); o.w = f2bf(v.w);
    ((ushort4*)out)[i] = o;
  }
}

// ------------------------------------------------- W [K][N] f32 -> Wt [N][K] bf16
__global__ __launch_bounds__(256) void transpose_w(
    const float* __restrict__ W, ushort* __restrict__ Wt, int K, int N) {
  __shared__ float tile[32][33];
  const int n0 = blockIdx.x * 32, k0 = blockIdx.y * 32;
  const int tx = threadIdx.x & 31, ty = threadIdx.x >> 5;  // ty 0..7
#pragma unroll
  for (int i = 0; i < 4; ++i)
    tile[ty + i * 8][tx] = W[(size_t)(k0 + ty + i * 8) * N + n0 + tx];
  __syncthreads();
#pragma unroll
  for (int i = 0; i < 4; ++i)
    Wt[(size_t)(n0 + ty + i * 8) * K + k0 + tx] = f2bf(tile[tx][ty + i * 8]);
}

// ------------------------------------------------------- QKV GEMM (R12, 128^2)
// A [M][K] bf16, Bt [N][K] bf16. BK=32, TRIPLE-buffered LDS (48KB -> 3
// blocks/CU). Counted-vmcnt pipeline: prologue stages tiles 0,1; iter t waits
// vmcnt(4) (own 4 loads for tile t; t+1 stays in flight), raw s_barrier,
// ds_read buf[t%3], issue stage(t+2), 16 MFMA. vmcnt(0) only at last iter.
// Swizzle f(row)=(row>>1)&3 on both pre-swizzled source and ds_read.
// XCD row-slab decode. Epilogue: QKV split (q pre-scaled 0.125*log2e, V^T
// key-permuted within 32-token chunks).
__global__ __launch_bounds__(256)
__attribute__((amdgpu_waves_per_eu(3, 3)))
void gemm_qkv(
    const ushort* __restrict__ A, const ushort* __restrict__ Bt,
    ushort* __restrict__ qb, ushort* __restrict__ kb, ushort* __restrict__ vb,
    int M, int N, int K) {
  __shared__ ushort As[3][128 * 32];
  __shared__ ushort Bs[3][128 * 32];
  const int tid = threadIdx.x;
  const int lane = tid & 63;
  const int w = tid >> 6;
  const int wr = w >> 1, wc = w & 1;
  const int l15 = lane & 15, lhi = lane >> 4;

  const int ncolt = N >> 7;
  const int rpx = (M >> 7) >> 3;
  const int b = blockIdx.x;
  const int xcd = b & 7;
  const int loc = b >> 3;
  const int rowg = loc / ncolt;
  const int colt = loc - rowg * ncolt;
  const int row0 = (xcd * rpx + rowg) * 128;
  const int col0 = colt * 128;

  const int cr = lane >> 2;
  const int sl = lane & 3;
  const int gofs = (sl ^ ((cr >> 1) & 3)) << 3;
  const ushort* gA = A  + (size_t)(row0 + w * 32 + cr) * K + gofs;
  const ushort* gB = Bt + (size_t)(col0 + w * 32 + cr) * K + gofs;
  const int lbase = (w * 32) * 32;

  f32x4 acc[4][4] = {};

#define G_STAGE(BUF, T)                                                      \
  {                                                                          \
    gload16(gA + (size_t)(T) * 32, &As[BUF][lbase]);                         \
    gload16(gA + (size_t)16 * K + (size_t)(T) * 32, &As[BUF][lbase + 512]);  \
    gload16(gB + (size_t)(T) * 32, &Bs[BUF][lbase]);                         \
    gload16(gB + (size_t)16 * K + (size_t)(T) * 32, &Bs[BUF][lbase + 512]);  \
  }

  const int nk = K >> 5;
  G_STAGE(0, 0)
  G_STAGE(1, 1)

  for (int t = 0; t < nk; ++t) {
    const int cur = t % 3;
    if (t + 1 < nk) {
      asm volatile("s_waitcnt vmcnt(4)" ::: "memory");
    } else {
      asm volatile("s_waitcnt vmcnt(0)" ::: "memory");
    }
    __builtin_amdgcn_s_barrier();

    bf16x8 af[4], bfr[4];
#pragma unroll
    for (int m = 0; m < 4; ++m) {
      const int row = wr * 64 + m * 16 + l15;
      af[m] = *(const bf16x8*)&As[cur][row * 32 + ((lhi ^ ((row >> 1) & 3)) << 3)];
    }
#pragma unroll
    for (int n = 0; n < 4; ++n) {
      const int row = wc * 64 + n * 16 + l15;
      bfr[n] = *(const bf16x8*)&Bs[cur][row * 32 + ((lhi ^ ((row >> 1) & 3)) << 3)];
    }

    if (t + 2 < nk) {
      const int nb = (t + 2) % 3;
      G_STAGE(nb, t + 2)
    }

    __builtin_amdgcn_s_setprio(1);
#pragma unroll
    for (int m = 0; m < 4; ++m)
#pragma unroll
      for (int n = 0; n < 4; ++n)
        acc[m][n] = MFMA_BF16(af[m], bfr[n], acc[m][n]);
    __builtin_amdgcn_s_setprio(0);
  }
#undef G_STAGE

  // QKV split epilogue. c in [0,3072): seg=c/1024, h=(c%1024)/64, d=c%64
  const float QSCALE = 0.18033688011112042f;  // (1/sqrt(64)) * log2(e)
#pragma unroll
  for (int m = 0; m < 4; ++m) {
    const int r0 = row0 + wr * 64 + m * 16 + lhi * 4;
    const int b_ = r0 >> 11;
    const int t0 = r0 & 2047;
#pragma unroll
    for (int n = 0; n < 4; ++n) {
      const int c = col0 + wc * 64 + n * 16 + l15;
      const int seg = c >> 10;
      const int cc = c & 1023;
      const int h = cc >> 6, d = cc & 63;
      const size_t bhi = (size_t)(b_ * 16 + h);
      if (seg == 0) {
#pragma unroll
        for (int j = 0; j < 4; ++j)
          qb[(bhi * 2048 + t0 + j) * 64 + d] = f2bf(acc[m][n][j] * QSCALE);
      } else if (seg == 1) {
#pragma unroll
        for (int j = 0; j < 4; ++j)
          kb[(bhi * 2048 + t0 + j) * 64 + d] = f2bf(acc[m][n][j]);
      } else {
        // permuted key position within the 32-token chunk (t0 % 4 == 0)
        const int pos = (t0 & ~31) + ((t0 & 12) << 1) + ((t0 >> 4) & 1) * 4;
        ushort4 pk;
        pk.x = f2bf(acc[m][n][0]);
        pk.y = f2bf(acc[m][n][1]);
        pk.z = f2bf(acc[m][n][2]);
        pk.w = f2bf(acc[m][n][3]);
        *(ushort4*)(vb + (bhi * 64 + d) * 2048 + pos) = pk;  // V^T key-permuted
      }
    }
  }
}

// ---------------------------------------------------- out-proj GEMM (R9, BK=64)
// A [M][K] bf16, Bt [N][K] bf16, C [M][N] fp32. 128x128 tile, BK=64,
// double-buffered LDS [2][128][64] (64KB -> 2 blocks/CU, waves_per_eu(2,2)).
// All 8 next-tile gload_lds issued before this tile's MFMAs; one
// __syncthreads per iteration (drain hidden under 32 MFMAs + 2nd block).
// Swizzle: 128B rows, granule sl ^ (row&7) (verified 0-conflict in R9).
__global__ __launch_bounds__(256)
__attribute__((amdgpu_waves_per_eu(2, 2)))
void gemm_out(
    const ushort* __restrict__ A, const ushort* __restrict__ Bt,
    float* __restrict__ C, int M, int N, int K) {
  __shared__ ushort As[2][128 * 64];
  __shared__ ushort Bs[2][128 * 64];
  const int tid = threadIdx.x;
  const int lane = tid & 63;
  const int w = tid >> 6;
  const int wr = w >> 1, wc = w & 1;
  const int l15 = lane & 15, lhi = lane >> 4;
  const int row0 = blockIdx.x * 128, col0 = blockIdx.y * 128;

  // staging: wave w stages rows [32w, 32w+32) of A and B as 4 chunks of 8 rows
  const int cr = lane >> 3;            // row within chunk
  const int sl = lane & 7;             // 16B granule within 128B row
  const int gofs = (sl ^ cr) << 3;     // pre-swizzled (row&7 == cr)
  const ushort* gA = A  + (size_t)(row0 + w * 32 + cr) * K + gofs;
  const ushort* gB = Bt + (size_t)(col0 + w * 32 + cr) * K + gofs;
  const int lbase = (w * 32) * 64;

  f32x4 acc[4][4] = {};

#define G_STAGE8(BUF, K0)                                                    \
  {                                                                          \
    _Pragma("unroll")                                                        \
    for (int i = 0; i < 4; ++i) {                                            \
      gload16(gA + (size_t)(i * 8) * K + (K0), &As[BUF][lbase + i * 512]);   \
      gload16(gB + (size_t)(i * 8) * K + (K0), &Bs[BUF][lbase + i * 512]);   \
    }                                                                        \
  }

  const int nk = K >> 6;
  G_STAGE8(0, 0)
  __syncthreads();

  for (int t = 0; t < nk; ++t) {
    const int cur = t & 1;
    if (t + 1 < nk) G_STAGE8(cur ^ 1, (t + 1) << 6)

#pragma unroll
    for (int kh = 0; kh < 2; ++kh) {
      bf16x8 af[4], bfr[4];
#pragma unroll
      for (int m = 0; m < 4; ++m) {
        const int row = wr * 64 + m * 16 + l15;
        const int s = kh * 4 + lhi;
        af[m] = *(const bf16x8*)&As[cur][row * 64 + ((s ^ (row & 7)) << 3)];
      }
#pragma unroll
      for (int n = 0; n < 4; ++n) {
        const int row = wc * 64 + n * 16 + l15;
        const int s = kh * 4 + lhi;
        bfr[n] = *(const bf16x8*)&Bs[cur][row * 64 + ((s ^ (row & 7)) << 3)];
      }
      __builtin_amdgcn_s_setprio(1);
#pragma unroll
      for (int m = 0; m < 4; ++m)
#pragma unroll
        for (int n = 0; n < 4; ++n)
          acc[m][n] = MFMA_BF16(af[m], bfr[n], acc[m][n]);
      __builtin_amdgcn_s_setprio(0);
    }
    __syncthreads();  // drains t+1's gload_lds under this tile's 32 MFMAs
  }
#undef G_STAGE8

#pragma unroll
  for (int m = 0; m < 4; ++m) {
    const int r0 = row0 + wr * 64 + m * 16 + lhi * 4;
#pragma unroll
    for (int n = 0; n < 4; ++n) {
      const int c = col0 + wc * 64 + n * 16 + l15;
#pragma unroll
      for (int j = 0; j < 4; ++j)
        C[(size_t)(r0 + j) * N + c] = acc[m][n][j];
    }
  }
}

// ------------------------------------------------------------- attention
// (unchanged from R8 — spill fixed via waves_per_eu(4,4) + de-arrayed state)
#define QK_TILE(SV, KT)                                                      \
  {                                                                          \
    const int krow = (KT) * 16 + l15;                                        \
    const int sw = krow & 7;                                                 \
    bf16x8 kf0 = *(const bf16x8*)&Ks[cur][krow * 64 + ((lhi ^ sw) * 8)];     \
    bf16x8 kf1 = *(const bf16x8*)&Ks[cur][krow * 64 + (((4 + lhi) ^ sw) * 8)];\
    f32x4 acc_ = {};                                                         \
    acc_ = MFMA_BF16(kf0, qf0, acc_);                                        \
    acc_ = MFMA_BF16(kf1, qf1, acc_);                                        \
    SV = acc_;                                                               \
  }

#define MASK_TILE(SV, KT)                                                    \
  {                                                                          \
    if (key0 + (KT) * 16 + lhi * 4 + 0 > qrow) SV[0] = -INFINITY;            \
    if (key0 + (KT) * 16 + lhi * 4 + 1 > qrow) SV[1] = -INFINITY;            \
    if (key0 + (KT) * 16 + lhi * 4 + 2 > qrow) SV[2] = -INFINITY;            \
    if (key0 + (KT) * 16 + lhi * 4 + 3 > qrow) SV[3] = -INFINITY;            \
  }

#define SM_TILE(SV, W0, W1)                                                  \
  {                                                                          \
    float p0 = exp2f(SV[0] - m_state);                                       \
    float p1 = exp2f(SV[1] - m_state);                                       \
    float p2 = exp2f(SV[2] - m_state);                                       \
    float p3 = exp2f(SV[3] - m_state);                                       \
    lloc += (p0 + p1) + (p2 + p3);                                           \
    W0 = cvt_pk_bf16(p0, p1);                                                \
    W1 = cvt_pk_bf16(p2, p3);                                                \
  }

#define PV_TILE(ON, N)                                                       \
  {                                                                          \
    const int vrow = (N) * 16 + l15;                                         \
    const int sw = vrow & 7;                                                 \
    bf16x8 vf0 = *(const bf16x8*)&Vs[cur][vrow * 64 + ((lhi ^ sw) * 8)];     \
    bf16x8 vf1 = *(const bf16x8*)&Vs[cur][vrow * 64 + (((4 + lhi) ^ sw) * 8)];\
    ON = MFMA_BF16(pf0, vf0, ON);                                            \
    ON = MFMA_BF16(pf1, vf1, ON);                                            \
  }

__global__ __launch_bounds__(256)
__attribute__((amdgpu_waves_per_eu(4, 4)))
void attn_kernel(
    const ushort* __restrict__ Qb, const ushort* __restrict__ Kb,
    const ushort* __restrict__ Vt, ushort* __restrict__ Ab) {
  const int bid = blockIdx.x;
  const int qt = 31 - (bid >> 6);
  const int bh = bid & 63;
  const int tid = threadIdx.x;
  const int lane = tid & 63;
  const int w = tid >> 6;
  const int l15 = lane & 15, lhi = lane >> 4;
  const int qloc = qt * 64 + w * 16;

  __shared__ ushort Ks[2][64 * 64];
  __shared__ ushort Vs[2][64 * 64];

  const size_t qkbase = (size_t)bh * (2048 * 64);
  const size_t vtb = (size_t)bh * (64 * 2048);

  const int srow = w * 16 + (lane >> 3);
  const int sd0 = lane & 7;
  const int slot = (sd0 ^ (srow & 7)) * 8;

  const ushort* kp0 = Kb + qkbase + (size_t)srow * 64 + sd0 * 8;
  const ushort* kp1 = kp0 + 8 * 64;
  const ushort* vp0 = Vt + vtb + (size_t)srow * 2048 + sd0 * 8;
  const ushort* vp1 = vp0 + 8 * 2048;

  bf16x8 qf0 = *(const bf16x8*)(Qb + qkbase + (size_t)(qloc + l15) * 64 + lhi * 8);
  bf16x8 qf1 = *(const bf16x8*)(Qb + qkbase + (size_t)(qloc + l15) * 64 + 32 + lhi * 8);

  uint4 kr0 = *(const uint4*)kp0;
  uint4 kr1 = *(const uint4*)kp1;
  uint4 vr0 = *(const uint4*)vp0;
  uint4 vr1 = *(const uint4*)vp1;
  *(uint4*)&Ks[0][srow * 64 + slot] = kr0;
  *(uint4*)&Ks[0][(srow + 8) * 64 + slot] = kr1;
  *(uint4*)&Vs[0][srow * 64 + slot] = vr0;
  *(uint4*)&Vs[0][(srow + 8) * 64 + slot] = vr1;
  __syncthreads();

  float m_state = -INFINITY, l_state = 0.f;
  f32x4 o0 = {}, o1 = {}, o2 = {}, o3 = {};
  const int qrow = qloc + l15;
  int cur = 0;

  for (int kbt = 0; kbt <= qt; ++kbt) {
    const int key0 = kbt * 64;
    const bool last = (kbt == qt);

    if (!last) {
      const size_t koff = (size_t)(kbt + 1) * 64 * 64;
      kr0 = *(const uint4*)(kp0 + koff);
      kr1 = *(const uint4*)(kp1 + koff);
      vr0 = *(const uint4*)(vp0 + (kbt + 1) * 64);
      vr1 = *(const uint4*)(vp1 + (kbt + 1) * 64);
    }

    f32x4 s0, s1, s2, s3;
    __builtin_amdgcn_s_setprio(1);
    QK_TILE(s0, 0)
    QK_TILE(s1, 1)
    QK_TILE(s2, 2)
    QK_TILE(s3, 3)
    __builtin_amdgcn_s_setprio(0);

    if (last) {
      MASK_TILE(s0, 0)
      MASK_TILE(s1, 1)
      MASK_TILE(s2, 2)
      MASK_TILE(s3, 3)
    }

    float t0 = fmaxf(fmaxf(s0[0], s0[1]), fmaxf(s0[2], s0[3]));
    float t1 = fmaxf(fmaxf(s1[0], s1[1]), fmaxf(s1[2], s1[3]));
    float t2 = fmaxf(fmaxf(s2[0], s2[1]), fmaxf(s2[2], s2[3]));
    float t3 = fmaxf(fmaxf(s3[0], s3[1]), fmaxf(s3[2], s3[3]));
    float tmax = fmaxf(fmaxf(t0, t1), fmaxf(t2, t3));
    tmax = fmaxf(tmax, __shfl_xor(tmax, 16));
    tmax = fmaxf(tmax, __shfl_xor(tmax, 32));

    if (!__all(tmax <= m_state + 8.0f)) {
      const float mnew = fmaxf(m_state, tmax);
      const float alpha = exp2f(m_state - mnew);
      const float a0 = __shfl(alpha, lhi * 4 + 0);
      const float a1 = __shfl(alpha, lhi * 4 + 1);
      const float a2 = __shfl(alpha, lhi * 4 + 2);
      const float a3 = __shfl(alpha, lhi * 4 + 3);
      o0[0] *= a0; o0[1] *= a1; o0[2] *= a2; o0[3] *= a3;
      o1[0] *= a0; o1[1] *= a1; o1[2] *= a2; o1[3] *= a3;
      o2[0] *= a0; o2[1] *= a1; o2[2] *= a2; o2[3] *= a3;
      o3[0] *= a0; o3[1] *= a1; o3[2] *= a2; o3[3] *= a3;
      l_state *= alpha;
      m_state = mnew;
    }

    float lloc = 0.f;
    uint32_t w0, w1, w2, w3, w4, w5, w6, w7;
    SM_TILE(s0, w0, w1)
    SM_TILE(s1, w2, w3)
    SM_TILE(s2, w4, w5)
    SM_TILE(s3, w6, w7)
    lloc += __shfl_xor(lloc, 16);
    lloc += __shfl_xor(lloc, 32);
    l_state += lloc;

    u32x4 pw0 = {w0, w1, w2, w3};
    u32x4 pw1 = {w4, w5, w6, w7};
    bf16x8 pf0 = __builtin_bit_cast(bf16x8, pw0);
    bf16x8 pf1 = __builtin_bit_cast(bf16x8, pw1);

    __builtin_amdgcn_s_setprio(1);
    PV_TILE(o0, 0)
    PV_TILE(o1, 1)
    PV_TILE(o2, 2)
    PV_TILE(o3, 3)
    __builtin_amdgcn_s_setprio(0);

    if (!last) {
      const int nxt = cur ^ 1;
      *(uint4*)&Ks[nxt][srow * 64 + slot] = kr0;
      *(uint4*)&Ks[nxt][(srow + 8) * 64 + slot] = kr1;
      *(uint4*)&Vs[nxt][srow * 64 + slot] = vr0;
      *(uint4*)&Vs[nxt][(srow + 8) * 64 + slot] = vr1;
      cur = nxt;
      __syncthreads();
    }
  }

  const int b_ = bh >> 4, h_ = bh & 15;
#pragma unroll
  for (int j = 0; j < 4; ++j) {
    const float linv = 1.0f / __shfl(l_state, lhi * 4 + j);
    const int t = qloc + lhi * 4 + j;
    const size_t ro = ((size_t)b_ * 2048 + t) * 1024 + h_ * 64;
    Ab[ro + 0 * 16 + l15] = f2bf(o0[j] * linv);
    Ab[ro + 1 * 16 + l15] = f2bf(o1[j] * linv);
    Ab[ro + 2 * 16 + l15] = f2bf(o2[j] * linv);
    Ab[ro + 3 * 16 + l15] = f2bf(o3[j] * linv);
  }
}

// ---------------------------------------------------------------- launch
extern "C" void kernel_launch(void* const* d_in, const int* in_sizes, int n_in,
                              void* d_out, int out_size, void* d_ws, size_t ws_size,
                              hipStream_t stream) {
  const float* x = (const float*)d_in[0];
  const float* Wqkv = (const float*)d_in[1];
  const float* Wout = (const float*)d_in[2];
  float* out = (float*)d_out;

  // workspace layout (bf16 elements), total ~88 MB
  ushort* xb    = (ushort*)d_ws;                     // [8192][1024]
  ushort* wqkvT = xb + (size_t)8192 * 1024;          // [3072][1024]
  ushort* woutT = wqkvT + (size_t)3072 * 1024;       // [1024][1024]
  ushort* qb    = woutT + (size_t)1024 * 1024;       // [64][2048][64]
  ushort* kbuf  = qb + (size_t)64 * 2048 * 64;       // [64][2048][64]
  ushort* vbuf  = kbuf + (size_t)64 * 2048 * 64;     // [64][64][2048] (V^T, key-permuted)
  ushort* ab    = vbuf + (size_t)64 * 2048 * 64;     // [8192][1024]

  convert_f32_bf16<<<8192, 256, 0, stream>>>(x, xb, 8192 * 1024 / 4);
  transpose_w<<<dim3(96, 32), 256, 0, stream>>>(Wqkv, wqkvT, 1024, 3072);
  transpose_w<<<dim3(32, 32), 256, 0, stream>>>(Wout, woutT, 1024, 1024);
  gemm_qkv<<<1536, 256, 0, stream>>>(
      xb, wqkvT, qb, kbuf, vbuf, 8192, 3072, 1024);
  attn_kernel<<<2048, 256, 0, stream>>>(qb, kbuf, vbuf, ab);
  gemm_out<<<dim3(64, 8), 256, 0, stream>>>(
      ab, woutT, out, 8192, 1024, 1024);
}

// Round 15
// 173.270 us; speedup vs baseline: 1.1189x; 1.0279x over previous
//
#include <hip/hip_runtime.h>
#include <hip/hip_bf16.h>
#include <cstdint>

// Causal self-attention: x[4,2048,1024] @ Wqkv[1024,3072] -> QKV -> 16-head
// causal attention (HD=64) -> @ Wout[1024,1024] -> out fp32.
// R15: second (derived-waits) attempt at the 256^2 8-wave phase-split QKV
// GEMM. Differences vs the failed R13 port: staging is STAGGERED one
// consumption-unit per phase in consumption order (A-MH0,B-NH0,B-NH1,A-MH1;
// 2 gload_lds/thread each), waits are counted vmcnt(4) at phases 0/1/2
// (steady-state 6 outstanding -> wait leaves 4 in flight; NEVER 0 mid-loop),
// no wait/barrier at phase 3. sched_barrier(0) after each barrier (rule #18).
// Layout/swizzle/epilogue identical to R13 (correctness-verified).
// G1 = R9 BK=64 kernel; attention = R8. Pre-kernels unchanged.

typedef __attribute__((ext_vector_type(8))) short bf16x8;
typedef __attribute__((ext_vector_type(4))) float f32x4;
typedef __attribute__((ext_vector_type(4))) uint32_t u32x4;

#define MFMA_BF16(a, b, c) __builtin_amdgcn_mfma_f32_16x16x32_bf16((a), (b), (c), 0, 0, 0)

__device__ __forceinline__ ushort f2bf(float f) {
  union { float f; uint32_t u; } x;
  x.f = f;
  uint32_t u = x.u;
  return (ushort)((u + 0x7FFFu + ((u >> 16) & 1u)) >> 16);
}

__device__ __forceinline__ uint32_t cvt_pk_bf16(float lo, float hi) {
  uint32_t r;
  asm("v_cvt_pk_bf16_f32 %0, %1, %2" : "=v"(r) : "v"(lo), "v"(hi));
  return r;
}

__device__ __forceinline__ void gload16(const ushort* g, ushort* l) {
  __builtin_amdgcn_global_load_lds(
      (const __attribute__((address_space(1))) void*)g,
      (__attribute__((address_space(3))) void*)l, 16, 0, 0);
}

// ---------------------------------------------------------------- convert x
__global__ __launch_bounds__(256) void convert_f32_bf16(
    const float* __restrict__ in, ushort* __restrict__ out, int n4) {
  int i = blockIdx.x * 256 + threadIdx.x;
  if (i < n4) {
    float4 v = ((const float4*)in)[i];
    ushort4 o;
    o.x = f2bf(v.x); o.y = f2bf(v.y); o.z = f2bf(v.z); o.w = f2bf(v.w);
    ((ushort4*)out)[i] = o;
  }
}

// ------------------------------------------------- W [K][N] f32 -> Wt [N][K] bf16
__global__ __launch_bounds__(256) void transpose_w(
    const float* __restrict__ W, ushort* __restrict__ Wt, int K, int N) {
  __shared__ float tile[32][33];
  const int n0 = blockIdx.x * 32, k0 = blockIdx.y * 32;
  const int tx = threadIdx.x & 31, ty = threadIdx.x >> 5;  // ty 0..7
#pragma unroll
  for (int i = 0; i < 4; ++i)
    tile[ty + i * 8][tx] = W[(size_t)(k0 + ty + i * 8) * N + n0 + tx];
  __syncthreads();
#pragma unroll
  for (int i = 0; i < 4; ++i)
    Wt[(size_t)(n0 + ty + i * 8) * K + k0 + tx] = f2bf(tile[tx][ty + i * 8]);
}

// ---------------------------------------------------- 256x256 8-phase GEMM (QKV)
// A [M][K] bf16, Bt [N][K] bf16. 512 threads = 8 waves (2M x 4N); per-wave
// C = 128x64 (acc[8][4]). LDS [2][256][64] per operand = 128KB (1 block/CU).
// Stage units (each = 2 gload_lds/thread, issued one per phase, tile t+1):
//   phase0: A-MH0 (rows 0-63,128-191)   consumed at phase0 of t+1 (dist 4)
//   phase1: B-NH0 (rows q*64+0..31)     consumed at phase0 of t+1 (dist 3)
//   phase2: B-NH1 (rows q*64+32..63)    consumed at phase1 of t+1 (dist 3)
//   phase3: A-MH1 (rows 64-127,192-255) consumed at phase2 of t+1 (dist 3)
// Waits: vmcnt(4) at phases 0,1,2 (6 outstanding -> needed unit lands, 4 stay
// in flight); phase 3 has no ds_read -> no wait, no barrier. Last tile:
// vmcnt(4)/(2)/(0). Swizzle granule^(row&7) (pre-swizzled source, linear DMA).

#define LD_AF(MH)                                                            \
  {                                                                          \
    _Pragma("unroll")                                                        \
    for (int m = 0; m < 4; ++m) {                                            \
      const int row = wr * 128 + (MH) * 64 + m * 16 + l15;                   \
      _Pragma("unroll")                                                      \
      for (int kk = 0; kk < 2; ++kk)                                         \
        af[m][kk] = *(const bf16x8*)&as[row * 64 +                           \
                     (((kk * 4 + lhi) ^ (row & 7)) << 3)];                   \
    }                                                                        \
  }

#define LD_BF(DST, NH)                                                       \
  {                                                                          \
    _Pragma("unroll")                                                        \
    for (int n = 0; n < 2; ++n) {                                            \
      const int row = wc * 64 + (NH) * 32 + n * 16 + l15;                    \
      _Pragma("unroll")                                                      \
      for (int kk = 0; kk < 2; ++kk)                                         \
        DST[n][kk] = *(const bf16x8*)&bs[row * 64 +                          \
                     (((kk * 4 + lhi) ^ (row & 7)) << 3)];                   \
    }                                                                        \
  }

#define MFMA16(MH, NH, BF)                                                   \
  {                                                                          \
    __builtin_amdgcn_s_setprio(1);                                           \
    _Pragma("unroll")                                                        \
    for (int m = 0; m < 4; ++m)                                              \
      _Pragma("unroll")                                                      \
      for (int n = 0; n < 2; ++n)                                            \
        _Pragma("unroll")                                                    \
        for (int kk = 0; kk < 2; ++kk)                                       \
          acc[(MH) * 4 + m][(NH) * 2 + n] = MFMA_BF16(                       \
              af[m][kk], BF[n][kk], acc[(MH) * 4 + m][(NH) * 2 + n]);        \
    __builtin_amdgcn_s_setprio(0);                                           \
  }

__global__ __launch_bounds__(512)
__attribute__((amdgpu_waves_per_eu(2, 2)))
void gemm256_qkv(
    const ushort* __restrict__ A, const ushort* __restrict__ Bt,
    ushort* __restrict__ qb, ushort* __restrict__ kb, ushort* __restrict__ vb,
    int M, int N, int K) {
  __shared__ ushort As[2][256 * 64];  // 64 KB
  __shared__ ushort Bs[2][256 * 64];  // 64 KB
  const int tid = threadIdx.x;
  const int lane = tid & 63;
  const int w = tid >> 6;              // 0..7
  const int wr = w >> 2, wc = w & 3;   // 2M x 4N
  const int l15 = lane & 15, lhi = lane >> 4;

  // XCD row-slab decode (grid 384 = 8 XCD * 48; M/256=32 -> 4 row-tiles/XCD)
  const int ncolt = N >> 8;            // 12
  const int rpx = (M >> 8) >> 3;       // 4
  const int b = blockIdx.x;
  const int xcd = b & 7;
  const int loc = b >> 3;
  const int rowg = loc / ncolt;
  const int colt = loc - rowg * ncolt;
  const int row0 = (xcd * rpx + rowg) * 256;
  const int col0 = colt * 256;

  // staging geometry: per unit, wave w owns 2 chunks (8 rows x 64 cols = 1KB).
  // lane: cr8 = row-in-chunk, sl8 = linear granule; global granule pre-swizzled.
  const int cr8 = lane >> 3;
  const int sl8 = lane & 7;
  const int gcol = (sl8 ^ cr8) << 3;   // (row&7)==cr8 for 8-aligned rowbases
  const int rA = (w & 3) * 16 + (w >> 2) * 128;  // A-MH0 chunk rowbase
  const int rB = (w & 1) * 16 + (w >> 1) * 64;   // B-NH0 chunk rowbase
  const ushort* gA0u = A  + (size_t)(row0 + rA + cr8) * K + gcol;
  const ushort* gB0u = Bt + (size_t)(col0 + rB + cr8) * K + gcol;
  const ushort* gA1u = gA0u + (size_t)64 * K;
  const ushort* gB1u = gB0u + (size_t)32 * K;
  const int lA0 = rA * 64;             // wave-uniform LDS ushort base
  const int lB0 = rB * 64;
  const int lA1 = lA0 + 64 * 64;
  const int lB1 = lB0 + 32 * 64;

#define STAGE_A0(BUF, T)                                                     \
  { gload16(gA0u + (size_t)(T) * 64, &As[BUF][lA0]);                         \
    gload16(gA0u + (size_t)8 * K + (size_t)(T) * 64, &As[BUF][lA0 + 512]); }
#define STAGE_B0(BUF, T)                                                     \
  { gload16(gB0u + (size_t)(T) * 64, &Bs[BUF][lB0]);                         \
    gload16(gB0u + (size_t)8 * K + (size_t)(T) * 64, &Bs[BUF][lB0 + 512]); }
#define STAGE_B1(BUF, T)                                                     \
  { gload16(gB1u + (size_t)(T) * 64, &Bs[BUF][lB1]);                         \
    gload16(gB1u + (size_t)8 * K + (size_t)(T) * 64, &Bs[BUF][lB1 + 512]); }
#define STAGE_A1(BUF, T)                                                     \
  { gload16(gA1u + (size_t)(T) * 64, &As[BUF][lA1]);                         \
    gload16(gA1u + (size_t)8 * K + (size_t)(T) * 64, &As[BUF][lA1 + 512]); }

  f32x4 acc[8][4] = {};

  const int nk = K >> 6;               // 16
  // prologue: tile 0 units in consumption order (8 loads outstanding)
  STAGE_A0(0, 0)
  STAGE_B0(0, 0)
  STAGE_B1(0, 0)
  STAGE_A1(0, 0)

  for (int t = 0; t < nk; ++t) {
    const int cur = t & 1;
    const int nxt = cur ^ 1;
    const ushort* as = &As[cur][0];
    const ushort* bs = &Bs[cur][0];
    const bool pre = (t + 1 < nk);     // block-uniform

    bf16x8 af[4][2], bf0[2][2], bf1[2][2];

    // ---- phase 0: needs A-MH0 + B-NH0 of tile t (6 outstanding -> 4)
    asm volatile("s_waitcnt vmcnt(4)" ::: "memory");
    __builtin_amdgcn_s_barrier();
    __builtin_amdgcn_sched_barrier(0);
    LD_AF(0)
    LD_BF(bf0, 0)
    if (pre) STAGE_A0(nxt, t + 1)
    MFMA16(0, 0, bf0)

    // ---- phase 1: needs B-NH1 of tile t
    if (pre) {
      asm volatile("s_waitcnt vmcnt(4)" ::: "memory");
    } else {
      asm volatile("s_waitcnt vmcnt(2)" ::: "memory");
    }
    __builtin_amdgcn_s_barrier();
    __builtin_amdgcn_sched_barrier(0);
    LD_BF(bf1, 1)
    if (pre) STAGE_B0(nxt, t + 1)
    MFMA16(0, 1, bf1)

    // ---- phase 2: needs A-MH1 of tile t
    if (pre) {
      asm volatile("s_waitcnt vmcnt(4)" ::: "memory");
    } else {
      asm volatile("s_waitcnt vmcnt(0)" ::: "memory");
    }
    __builtin_amdgcn_s_barrier();
    __builtin_amdgcn_sched_barrier(0);
    LD_AF(1)
    if (pre) STAGE_B1(nxt, t + 1)
    MFMA16(1, 1, bf1)

    // ---- phase 3: register-reuse only (no ds_read, no wait, no barrier)
    if (pre) STAGE_A1(nxt, t + 1)
    MFMA16(1, 0, bf0)
  }
#undef STAGE_A0
#undef STAGE_B0
#undef STAGE_B1
#undef STAGE_A1

  // ---- QKV split epilogue (c: seg=c/1024, h=(c%1024)/64, d=c%64)
  const float QSCALE = 0.18033688011112042f;  // (1/sqrt(64)) * log2(e)
#pragma unroll
  for (int m = 0; m < 8; ++m) {
    const int r0 = row0 + wr * 128 + m * 16 + lhi * 4;
    const int b_ = r0 >> 11;
    const int t0 = r0 & 2047;
#pragma unroll
    for (int n = 0; n < 4; ++n) {
      const int c = col0 + wc * 64 + n * 16 + l15;
      const int seg = c >> 10;
      const int cc = c & 1023;
      const int h = cc >> 6, d = cc & 63;
      const size_t bhi = (size_t)(b_ * 16 + h);
      if (seg == 0) {
#pragma unroll
        for (int j = 0; j < 4; ++j)
          qb[(bhi * 2048 + t0 + j) * 64 + d] = f2bf(acc[m][n][j] * QSCALE);
      } else if (seg == 1) {
#pragma unroll
        for (int j = 0; j < 4; ++j)
          kb[(bhi * 2048 + t0 + j) * 64 + d] = f2bf(acc[m][n][j]);
      } else {
        // permuted key position within the 32-token chunk (t0 % 4 == 0)
        const int pos = (t0 & ~31) + ((t0 & 12) << 1) + ((t0 >> 4) & 1) * 4;
        ushort4 pk;
        pk.x = f2bf(acc[m][n][0]);
        pk.y = f2bf(acc[m][n][1]);
        pk.z = f2bf(acc[m][n][2]);
        pk.w = f2bf(acc[m][n][3]);
        *(ushort4*)(vb + (bhi * 64 + d) * 2048 + pos) = pk;  // V^T key-permuted
      }
    }
  }
}

// ---------------------------------------------------- out-proj GEMM (R9, BK=64)
__global__ __launch_bounds__(256)
__attribute__((amdgpu_waves_per_eu(2, 2)))
void gemm_out(
    const ushort* __restrict__ A, const ushort* __restrict__ Bt,
    float* __restrict__ C, int M, int N, int K) {
  __shared__ ushort As[2][128 * 64];
  __shared__ ushort Bs[2][128 * 64];
  const int tid = threadIdx.x;
  const int lane = tid & 63;
  const int w = tid >> 6;
  const int wr = w >> 1, wc = w & 1;
  const int l15 = lane & 15, lhi = lane >> 4;
  const int row0 = blockIdx.x * 128, col0 = blockIdx.y * 128;

  const int cr = lane >> 3;
  const int sl = lane & 7;
  const int gofs = (sl ^ cr) << 3;
  const ushort* gA = A  + (size_t)(row0 + w * 32 + cr) * K + gofs;
  const ushort* gB = Bt + (size_t)(col0 + w * 32 + cr) * K + gofs;
  const int lbase = (w * 32) * 64;

  f32x4 acc[4][4] = {};

#define G_STAGE8(BUF, K0)                                                    \
  {                                                                          \
    _Pragma("unroll")                                                        \
    for (int i = 0; i < 4; ++i) {                                            \
      gload16(gA + (size_t)(i * 8) * K + (K0), &As[BUF][lbase + i * 512]);   \
      gload16(gB + (size_t)(i * 8) * K + (K0), &Bs[BUF][lbase + i * 512]);   \
    }                                                                        \
  }

  const int nk = K >> 6;
  G_STAGE8(0, 0)
  __syncthreads();

  for (int t = 0; t < nk; ++t) {
    const int cur = t & 1;
    if (t + 1 < nk) G_STAGE8(cur ^ 1, (t + 1) << 6)

#pragma unroll
    for (int kh = 0; kh < 2; ++kh) {
      bf16x8 af[4], bfr[4];
#pragma unroll
      for (int m = 0; m < 4; ++m) {
        const int row = wr * 64 + m * 16 + l15;
        const int s = kh * 4 + lhi;
        af[m] = *(const bf16x8*)&As[cur][row * 64 + ((s ^ (row & 7)) << 3)];
      }
#pragma unroll
      for (int n = 0; n < 4; ++n) {
        const int row = wc * 64 + n * 16 + l15;
        const int s = kh * 4 + lhi;
        bfr[n] = *(const bf16x8*)&Bs[cur][row * 64 + ((s ^ (row & 7)) << 3)];
      }
      __builtin_amdgcn_s_setprio(1);
#pragma unroll
      for (int m = 0; m < 4; ++m)
#pragma unroll
        for (int n = 0; n < 4; ++n)
          acc[m][n] = MFMA_BF16(af[m], bfr[n], acc[m][n]);
      __builtin_amdgcn_s_setprio(0);
    }
    __syncthreads();
  }
#undef G_STAGE8

#pragma unroll
  for (int m = 0; m < 4; ++m) {
    const int r0 = row0 + wr * 64 + m * 16 + lhi * 4;
#pragma unroll
    for (int n = 0; n < 4; ++n) {
      const int c = col0 + wc * 64 + n * 16 + l15;
#pragma unroll
      for (int j = 0; j < 4; ++j)
        C[(size_t)(r0 + j) * N + c] = acc[m][n][j];
    }
  }
}

// ------------------------------------------------------------- attention (R8)
#define QK_TILE(SV, KT)                                                      \
  {                                                                          \
    const int krow = (KT) * 16 + l15;                                        \
    const int sw = krow & 7;                                                 \
    bf16x8 kf0 = *(const bf16x8*)&Ks[cur][krow * 64 + ((lhi ^ sw) * 8)];     \
    bf16x8 kf1 = *(const bf16x8*)&Ks[cur][krow * 64 + (((4 + lhi) ^ sw) * 8)];\
    f32x4 acc_ = {};                                                         \
    acc_ = MFMA_BF16(kf0, qf0, acc_);                                        \
    acc_ = MFMA_BF16(kf1, qf1, acc_);                                        \
    SV = acc_;                                                               \
  }

#define MASK_TILE(SV, KT)                                                    \
  {                                                                          \
    if (key0 + (KT) * 16 + lhi * 4 + 0 > qrow) SV[0] = -INFINITY;            \
    if (key0 + (KT) * 16 + lhi * 4 + 1 > qrow) SV[1] = -INFINITY;            \
    if (key0 + (KT) * 16 + lhi * 4 + 2 > qrow) SV[2] = -INFINITY;            \
    if (key0 + (KT) * 16 + lhi * 4 + 3 > qrow) SV[3] = -INFINITY;            \
  }

#define SM_TILE(SV, W0, W1)                                                  \
  {                                                                          \
    float p0 = exp2f(SV[0] - m_state);                                       \
    float p1 = exp2f(SV[1] - m_state);                                       \
    float p2 = exp2f(SV[2] - m_state);                                       \
    float p3 = exp2f(SV[3] - m_state);                                       \
    lloc += (p0 + p1) + (p2 + p3);                                           \
    W0 = cvt_pk_bf16(p0, p1);                                                \
    W1 = cvt_pk_bf16(p2, p3);                                                \
  }

#define PV_TILE(ON, N)                                                       \
  {                                                                          \
    const int vrow = (N) * 16 + l15;                                         \
    const int sw = vrow & 7;                                                 \
    bf16x8 vf0 = *(const bf16x8*)&Vs[cur][vrow * 64 + ((lhi ^ sw) * 8)];     \
    bf16x8 vf1 = *(const bf16x8*)&Vs[cur][vrow * 64 + (((4 + lhi) ^ sw) * 8)];\
    ON = MFMA_BF16(pf0, vf0, ON);                                            \
    ON = MFMA_BF16(pf1, vf1, ON);                                            \
  }

__global__ __launch_bounds__(256)
__attribute__((amdgpu_waves_per_eu(4, 4)))
void attn_kernel(
    const ushort* __restrict__ Qb, const ushort* __restrict__ Kb,
    const ushort* __restrict__ Vt, ushort* __restrict__ Ab) {
  const int bid = blockIdx.x;
  const int qt = 31 - (bid >> 6);
  const int bh = bid & 63;
  const int tid = threadIdx.x;
  const int lane = tid & 63;
  const int w = tid >> 6;
  const int l15 = lane & 15, lhi = lane >> 4;
  const int qloc = qt * 64 + w * 16;

  __shared__ ushort Ks[2][64 * 64];
  __shared__ ushort Vs[2][64 * 64];

  const size_t qkbase = (size_t)bh * (2048 * 64);
  const size_t vtb = (size_t)bh * (64 * 2048);

  const int srow = w * 16 + (lane >> 3);
  const int sd0 = lane & 7;
  const int slot = (sd0 ^ (srow & 7)) * 8;

  const ushort* kp0 = Kb + qkbase + (size_t)srow * 64 + sd0 * 8;
  const ushort* kp1 = kp0 + 8 * 64;
  const ushort* vp0 = Vt + vtb + (size_t)srow * 2048 + sd0 * 8;
  const ushort* vp1 = vp0 + 8 * 2048;

  bf16x8 qf0 = *(const bf16x8*)(Qb + qkbase + (size_t)(qloc + l15) * 64 + lhi * 8);
  bf16x8 qf1 = *(const bf16x8*)(Qb + qkbase + (size_t)(qloc + l15) * 64 + 32 + lhi * 8);

  uint4 kr0 = *(const uint4*)kp0;
  uint4 kr1 = *(const uint4*)kp1;
  uint4 vr0 = *(const uint4*)vp0;
  uint4 vr1 = *(const uint4*)vp1;
  *(uint4*)&Ks[0][srow * 64 + slot] = kr0;
  *(uint4*)&Ks[0][(srow + 8) * 64 + slot] = kr1;
  *(uint4*)&Vs[0][srow * 64 + slot] = vr0;
  *(uint4*)&Vs[0][(srow + 8) * 64 + slot] = vr1;
  __syncthreads();

  float m_state = -INFINITY, l_state = 0.f;
  f32x4 o0 = {}, o1 = {}, o2 = {}, o3 = {};
  const int qrow = qloc + l15;
  int cur = 0;

  for (int kbt = 0; kbt <= qt; ++kbt) {
    const int key0 = kbt * 64;
    const bool last = (kbt == qt);

    if (!last) {
      const size_t koff = (size_t)(kbt + 1) * 64 * 64;
      kr0 = *(const uint4*)(kp0 + koff);
      kr1 = *(const uint4*)(kp1 + koff);
      vr0 = *(const uint4*)(vp0 + (kbt + 1) * 64);
      vr1 = *(const uint4*)(vp1 + (kbt + 1) * 64);
    }

    f32x4 s0, s1, s2, s3;
    __builtin_amdgcn_s_setprio(1);
    QK_TILE(s0, 0)
    QK_TILE(s1, 1)
    QK_TILE(s2, 2)
    QK_TILE(s3, 3)
    __builtin_amdgcn_s_setprio(0);

    if (last) {
      MASK_TILE(s0, 0)
      MASK_TILE(s1, 1)
      MASK_TILE(s2, 2)
      MASK_TILE(s3, 3)
    }

    float t0 = fmaxf(fmaxf(s0[0], s0[1]), fmaxf(s0[2], s0[3]));
    float t1 = fmaxf(fmaxf(s1[0], s1[1]), fmaxf(s1[2], s1[3]));
    float t2 = fmaxf(fmaxf(s2[0], s2[1]), fmaxf(s2[2], s2[3]));
    float t3 = fmaxf(fmaxf(s3[0], s3[1]), fmaxf(s3[2], s3[3]));
    float tmax = fmaxf(fmaxf(t0, t1), fmaxf(t2, t3));
    tmax = fmaxf(tmax, __shfl_xor(tmax, 16));
    tmax = fmaxf(tmax, __shfl_xor(tmax, 32));

    if (!__all(tmax <= m_state + 8.0f)) {
      const float mnew = fmaxf(m_state, tmax);
      const float alpha = exp2f(m_state - mnew);
      const float a0 = __shfl(alpha, lhi * 4 + 0);
      const float a1 = __shfl(alpha, lhi * 4 + 1);
      const float a2 = __shfl(alpha, lhi * 4 + 2);
      const float a3 = __shfl(alpha, lhi * 4 + 3);
      o0[0] *= a0; o0[1] *= a1; o0[2] *= a2; o0[3] *= a3;
      o1[0] *= a0; o1[1] *= a1; o1[2] *= a2; o1[3] *= a3;
      o2[0] *= a0; o2[1] *= a1; o2[2] *= a2; o2[3] *= a3;
      o3[0] *= a0; o3[1] *= a1; o3[2] *= a2; o3[3] *= a3;
      l_state *= alpha;
      m_state = mnew;
    }

    float lloc = 0.f;
    uint32_t w0, w1, w2, w3, w4, w5, w6, w7;
    SM_TILE(s0, w0, w1)
    SM_TILE(s1, w2, w3)
    SM_TILE(s2, w4, w5)
    SM_TILE(s3, w6, w7)
    lloc += __shfl_xor(lloc, 16);
    lloc += __shfl_xor(lloc, 32);
    l_state += lloc;

    u32x4 pw0 = {w0, w1, w2, w3};
    u32x4 pw1 = {w4, w5, w6, w7};
    bf16x8 pf0 = __builtin_bit_cast(bf16x8, pw0);
    bf16x8 pf1 = __builtin_bit_cast(bf16x8, pw1);

    __builtin_amdgcn_s_setprio(1);
    PV_TILE(o0, 0)
    PV_TILE(o1, 1)
    PV_TILE(o2, 2)
    PV_TILE(o3, 3)
    __builtin_amdgcn_s_setprio(0);

    if (!last) {
      const int nxt = cur ^ 1;
      *(uint4*)&Ks[nxt][srow * 64 + slot] = kr0;
      *(uint4*)&Ks[nxt][(srow + 8) * 64 + slot] = kr1;
      *(uint4*)&Vs[nxt][srow * 64 + slot] = vr0;
      *(uint4*)&Vs[nxt][(srow + 8) * 64 + slot] = vr1;
      cur = nxt;
      __syncthreads();
    }
  }

  const int b_ = bh >> 4, h_ = bh & 15;
#pragma unroll
  for (int j = 0; j < 4; ++j) {
    const float linv = 1.0f / __shfl(l_state, lhi * 4 + j);
    const int t = qloc + lhi * 4 + j;
    const size_t ro = ((size_t)b_ * 2048 + t) * 1024 + h_ * 64;
    Ab[ro + 0 * 16 + l15] = f2bf(o0[j] * linv);
    Ab[ro + 1 * 16 + l15] = f2bf(o1[j] * linv);
    Ab[ro + 2 * 16 + l15] = f2bf(o2[j] * linv);
    Ab[ro + 3 * 16 + l15] = f2bf(o3[j] * linv);
  }
}

// ---------------------------------------------------------------- launch
extern "C" void kernel_launch(void* const* d_in, const int* in_sizes, int n_in,
                              void* d_out, int out_size, void* d_ws, size_t ws_size,
                              hipStream_t stream) {
  const float* x = (const float*)d_in[0];
  const float* Wqkv = (const float*)d_in[1];
  const float* Wout = (const float*)d_in[2];
  float* out = (float*)d_out;

  // workspace layout (bf16 elements), total ~88 MB
  ushort* xb    = (ushort*)d_ws;                     // [8192][1024]
  ushort* wqkvT = xb + (size_t)8192 * 1024;          // [3072][1024]
  ushort* woutT = wqkvT + (size_t)3072 * 1024;       // [1024][1024]
  ushort* qb    = woutT + (size_t)1024 * 1024;       // [64][2048][64]
  ushort* kbuf  = qb + (size_t)64 * 2048 * 64;       // [64][2048][64]
  ushort* vbuf  = kbuf + (size_t)64 * 2048 * 64;     // [64][64][2048] (V^T, key-permuted)
  ushort* ab    = vbuf + (size_t)64 * 2048 * 64;     // [8192][1024]

  convert_f32_bf16<<<8192, 256, 0, stream>>>(x, xb, 8192 * 1024 / 4);
  transpose_w<<<dim3(96, 32), 256, 0, stream>>>(Wqkv, wqkvT, 1024, 3072);
  transpose_w<<<dim3(32, 32), 256, 0, stream>>>(Wout, woutT, 1024, 1024);
  gemm256_qkv<<<384, 512, 0, stream>>>(
      xb, wqkvT, qb, kbuf, vbuf, 8192, 3072, 1024);
  attn_kernel<<<2048, 256, 0, stream>>>(qb, kbuf, vbuf, ab);
  gemm_out<<<dim3(64, 8), 256, 0, stream>>>(
      ab, woutT, out, 8192, 1024, 1024);
}